// Round 20
// baseline (192.730 us; speedup 1.0000x reference)
//
#include <hip/hip_runtime.h>
#include <stdint.h>

#define D_DIM 1024
#define NA_DIM 4096
#define NV_DIM 4096

typedef __bf16 bf16_t;
typedef __bf16 bf16x4 __attribute__((ext_vector_type(4)));
typedef __bf16 bf16x8 __attribute__((ext_vector_type(8)));
typedef float f32x4 __attribute__((ext_vector_type(4)));

// async global->LDS, 16B per lane; LDS base must be wave-uniform (HW adds lane*16)
__device__ __forceinline__ void gload_lds16(const void* g, void* lds) {
  __builtin_amdgcn_global_load_lds(
      (const __attribute__((address_space(1))) unsigned int*)g,
      (__attribute__((address_space(3))) unsigned int*)lds, 16, 0, 0);
}

// FINAL HYBRID (r19 consolidation): each stage uses its measured-best core.
//  - proj4/scores: 8-wave 256x256 "loose" core (r13/r15/r19: ~33us each at K=1024).
//  - att: 4-wave 128x128 BK=64 core, 64KB LDS -> 2 blocks/CU (r18/r19: ~73us;
//    co-resident blocks overlap LDS/MFMA phases across independent barrier domains).
//  - cvt merged to ONE launch (6 z-slices) to trim launch gaps (7 -> 6 dispatches).
// r12 lesson stands: no device-fence cross-block fusion on non-coherent-L2 XCDs.
#define VMW(N) asm volatile("s_waitcnt vmcnt(" #N ")" ::: "memory")
#define LKW(N) asm volatile("s_waitcnt lgkmcnt(" #N ")" ::: "memory")
#define BAR() asm volatile("s_barrier" ::: "memory")
#define MFMA(a, b, c) __builtin_amdgcn_mfma_f32_16x16x32_bf16((a), (b), (c), 0, 0, 0)

// ====== 8-wave 256x256 GEMM core, BK=64, 128KB LDS (1 block/CU) ======
// T2 swizzle: 16B chunk pc holds logical chunk pc ^ (row&7), both sides (conflicts=0).
__device__ __forceinline__ void gemm256_loose(const bf16_t* __restrict__ A,
                                              const bf16_t* __restrict__ B,
                                              int K, int bm, int bn,
                                              bf16_t* lds, f32x4 acc[8][4]) {
  const int tid = threadIdx.x;
  const int lane = tid & 63;
  const int wid = tid >> 6;
  const int wm = wid >> 2;   // 0..1 : wave row-half (128 rows)
  const int wn = wid & 3;    // 0..3 : wave col-quarter (64 cols)
  const int frow = lane & 15;
  const int hi = lane >> 4;
  const int fko = ((hi ^ (frow & 7)) << 3);

  const int sr = (wid << 4) + (lane >> 3);              // 0..127 within half-tile
  const int sc = (((lane & 7) ^ (lane >> 3)) << 3);
  const bf16_t* pAs = A + (size_t)(bm + sr) * K + sc;
  const bf16_t* pBs = B + (size_t)(bn + sr) * K + sc;
  const int dstW = wid << 10;

  const int aBase = (wm << 13) + frow * 64 + fko;
  const int bBase = 16384 + ((wn >> 1) << 13) + ((wn & 1) << 12) + frow * 64 + fko;

#define STG_A(kt, h, bufb) do { \
    const bf16_t* s_ = pAs + (size_t)((h) * 128) * K + (size_t)(kt) * 64; \
    bf16_t* d_ = lds + (bufb) * 32768 + (h) * 8192 + dstW; \
    gload_lds16(s_, d_); gload_lds16(s_ + (size_t)8 * K, d_ + 512); } while (0)
#define STG_B(kt, h, bufb) do { \
    const bf16_t* s_ = pBs + (size_t)((h) * 128) * K + (size_t)(kt) * 64; \
    bf16_t* d_ = lds + (bufb) * 32768 + 16384 + (h) * 8192 + dstW; \
    gload_lds16(s_, d_); gload_lds16(s_ + (size_t)8 * K, d_ + 512); } while (0)

#define TILE(P, T) do { \
    if ((T) + 1 < NT) { \
      STG_A((T) + 1, 0, (P) ^ 1); STG_A((T) + 1, 1, (P) ^ 1); \
      STG_B((T) + 1, 0, (P) ^ 1); STG_B((T) + 1, 1, (P) ^ 1); \
    } \
    { \
      const bf16_t* Lb_ = lds + (P) * 32768; \
      bf16x8 bf0[4], bf1[4]; \
      _Pragma("unroll") for (int fc = 0; fc < 4; ++fc) { \
        bf0[fc] = *(const bf16x8*)&Lb_[bBase + fc * 1024]; \
        bf1[fc] = *(const bf16x8*)&Lb_[(bBase ^ 32) + fc * 1024]; \
      } \
      _Pragma("unroll") for (int q = 0; q < 4; ++q) { \
        bf16x8 a0 = *(const bf16x8*)&Lb_[aBase + q * 2048]; \
        bf16x8 a1 = *(const bf16x8*)&Lb_[(aBase ^ 32) + q * 2048]; \
        bf16x8 a2 = *(const bf16x8*)&Lb_[aBase + q * 2048 + 1024]; \
        bf16x8 a3 = *(const bf16x8*)&Lb_[(aBase ^ 32) + q * 2048 + 1024]; \
        _Pragma("unroll") for (int fc = 0; fc < 4; ++fc) { \
          acc[q * 2][fc]     = MFMA(a0, bf0[fc], acc[q * 2][fc]); \
          acc[q * 2][fc]     = MFMA(a1, bf1[fc], acc[q * 2][fc]); \
          acc[q * 2 + 1][fc] = MFMA(a2, bf0[fc], acc[q * 2 + 1][fc]); \
          acc[q * 2 + 1][fc] = MFMA(a3, bf1[fc], acc[q * 2 + 1][fc]); \
        } \
      } \
    } \
    LKW(0); VMW(0); BAR(); \
  } while (0)

  const int NT = K >> 6;

  STG_A(0, 0, 0); STG_A(0, 1, 0); STG_B(0, 0, 0); STG_B(0, 1, 0);
  VMW(0);
  BAR();

  for (int it = 0; it < (NT >> 1); ++it) {
    TILE(0, 2 * it);
    TILE(1, 2 * it + 1);
  }
#undef TILE
#undef STG_A
#undef STG_B
}

// ====== 4-wave 128x128 GEMM core, BK=64, 64KB LDS -> 2 blocks/CU (att) ======
__device__ __forceinline__ void gemm4w64(const bf16_t* __restrict__ A,
                                         const bf16_t* __restrict__ B,
                                         int K, int bm, int bn,
                                         bf16_t* lds, f32x4 acc[4][4]) {
  const int tid = threadIdx.x;           // 0..255
  const int lane = tid & 63;
  const int wid = tid >> 6;              // 0..3
  const int wm = wid >> 1, wn = wid & 1;
  const int frow = lane & 15;
  const int hi = lane >> 4;
  const int fko = ((hi ^ (frow & 7)) << 3);

  const int r0 = tid >> 3;
  const int c0 = (((tid & 7) ^ (r0 & 7)) << 3);
  const bf16_t* pAs = A + (size_t)(bm + r0) * K + c0;
  const bf16_t* pBs = B + (size_t)(bn + r0) * K + c0;
  const int dstW = wid << 9;

  const int aBase = (wm << 12) + frow * 64 + fko;
  const int bBase = 8192 + (wn << 12) + frow * 64 + fko;

#define STG_A6(kt, bufb) do { \
    const bf16_t* s_ = pAs + (size_t)(kt) * 64; \
    bf16_t* d_ = lds + (bufb) * 16384 + dstW; \
    gload_lds16(s_, d_);                      gload_lds16(s_ + (size_t)32 * K, d_ + 2048); \
    gload_lds16(s_ + (size_t)64 * K, d_ + 4096); gload_lds16(s_ + (size_t)96 * K, d_ + 6144); } while (0)
#define STG_B6(kt, bufb) do { \
    const bf16_t* s_ = pBs + (size_t)(kt) * 64; \
    bf16_t* d_ = lds + (bufb) * 16384 + 8192 + dstW; \
    gload_lds16(s_, d_);                      gload_lds16(s_ + (size_t)32 * K, d_ + 2048); \
    gload_lds16(s_ + (size_t)64 * K, d_ + 4096); gload_lds16(s_ + (size_t)96 * K, d_ + 6144); } while (0)

#define TILE6(P, T) do { \
    if ((T) + 1 < NT) { STG_A6((T) + 1, (P) ^ 1); STG_B6((T) + 1, (P) ^ 1); } \
    { \
      const bf16_t* Lb_ = lds + (P) * 16384; \
      bf16x8 bf0[4], bf1[4]; \
      _Pragma("unroll") for (int fc = 0; fc < 4; ++fc) { \
        bf0[fc] = *(const bf16x8*)&Lb_[bBase + fc * 1024]; \
        bf1[fc] = *(const bf16x8*)&Lb_[(bBase ^ 32) + fc * 1024]; \
      } \
      _Pragma("unroll") for (int q = 0; q < 4; ++q) { \
        bf16x8 a0 = *(const bf16x8*)&Lb_[aBase + q * 1024]; \
        bf16x8 a1 = *(const bf16x8*)&Lb_[(aBase ^ 32) + q * 1024]; \
        _Pragma("unroll") for (int fc = 0; fc < 4; ++fc) { \
          acc[q][fc] = MFMA(a0, bf0[fc], acc[q][fc]); \
          acc[q][fc] = MFMA(a1, bf1[fc], acc[q][fc]); \
        } \
      } \
    } \
    LKW(0); VMW(0); BAR(); \
  } while (0)

  const int NT = K >> 6;

  STG_A6(0, 0); STG_B6(0, 0);
  VMW(0);
  BAR();

  for (int it = 0; it < (NT >> 1); ++it) {
    TILE6(0, 2 * it);
    TILE6(1, 2 * it + 1);
  }
#undef TILE6
#undef STG_A6
#undef STG_B6
}

// epilogues: verified C/D map: col = lane&15, row = (lane>>4)*4 + reg
template <int BF16OUT>
__device__ __forceinline__ void store256(void* Cv, int ldc, int bm, int bn, f32x4 acc[8][4]) {
  const int lane = threadIdx.x & 63;
  const int wid = threadIdx.x >> 6;
  const int wm = wid >> 2, wn = wid & 3;
  const int frow = lane & 15, hi = lane >> 4;
  const int row0 = bm + wm * 128 + hi * 4;
  const int col0 = bn + wn * 64 + frow;
#pragma unroll
  for (int rf = 0; rf < 8; ++rf)
#pragma unroll
    for (int fc = 0; fc < 4; ++fc)
#pragma unroll
      for (int r = 0; r < 4; ++r) {
        size_t idx = (size_t)(row0 + rf * 16 + r) * ldc + (col0 + fc * 16);
        if constexpr (BF16OUT) ((bf16_t*)Cv)[idx] = (bf16_t)acc[rf][fc][r];
        else ((float*)Cv)[idx] = acc[rf][fc][r];
      }
}

__device__ __forceinline__ void store256T(bf16_t* CT, int ldcT, int bm, int bn, f32x4 acc[8][4]) {
  const int lane = threadIdx.x & 63;
  const int wid = threadIdx.x >> 6;
  const int wm = wid >> 2, wn = wid & 3;
  const int frow = lane & 15, hi = lane >> 4;
  const int row0 = bm + wm * 128 + hi * 4;
  const int col0 = bn + wn * 64 + frow;
#pragma unroll
  for (int rf = 0; rf < 8; ++rf)
#pragma unroll
    for (int fc = 0; fc < 4; ++fc) {
      bf16x4 v;
#pragma unroll
      for (int r = 0; r < 4; ++r) v[r] = (bf16_t)acc[rf][fc][r];
      *(bf16x4*)(&CT[(size_t)(col0 + fc * 16) * ldcT + row0 + rf * 16]) = v;
    }
}

// ---------------- batched projections (8-wave 256^2 core); z=1,3 TRANSPOSED ----------
__global__ __launch_bounds__(512, 1) void gemm_proj4(
    const bf16_t* __restrict__ Xa, const bf16_t* __restrict__ Xv,
    const bf16_t* __restrict__ W0, const bf16_t* __restrict__ W1,
    const bf16_t* __restrict__ W2, const bf16_t* __restrict__ W3,
    bf16_t* __restrict__ C0, bf16_t* __restrict__ C1T,
    bf16_t* __restrict__ C2, bf16_t* __restrict__ C3T) {
  __shared__ bf16_t lds[65536];
  const int z = blockIdx.z;
  const bf16_t* A = (z < 2) ? Xa : Xv;
  const bf16_t* B = (z == 0) ? W0 : (z == 1) ? W1 : (z == 2) ? W2 : W3;
  f32x4 acc[8][4] = {};
  const int bm = blockIdx.x * 256, bn = blockIdx.y * 256;
  gemm256_loose(A, B, D_DIM, bm, bn, lds, acc);
  if (z == 0) store256<1>(C0, D_DIM, bm, bn, acc);
  else if (z == 1) store256T(C1T, NA_DIM, bm, bn, acc);
  else if (z == 2) store256<1>(C2, D_DIM, bm, bn, acc);
  else store256T(C3T, NV_DIM, bm, bn, acc);
}

// ---------------- scores GEMM (8-wave 256^2 core) ----------------
__global__ __launch_bounds__(512, 1) void gemm_scores(const bf16_t* __restrict__ A,
                                                      const bf16_t* __restrict__ B,
                                                      float* __restrict__ C) {
  __shared__ bf16_t lds[65536];
  f32x4 acc[8][4] = {};
  gemm256_loose(A, B, D_DIM, blockIdx.x * 256, blockIdx.y * 256, lds, acc);
  store256<0>(C, NV_DIM, blockIdx.x * 256, blockIdx.y * 256, acc);
}

// ------- stages 4/5 (4-wave 128^2 core, 2 blocks/CU), full K, fused residual -------
__global__ __launch_bounds__(256, 2) void gemm_att(
    const bf16_t* __restrict__ alpha, const bf16_t* __restrict__ bvT,
    const bf16_t* __restrict__ alphaT, const bf16_t* __restrict__ aaT,
    const float* __restrict__ resA, const float* __restrict__ resV,
    float* __restrict__ out) {
  __shared__ bf16_t lds[32768];
  const int z = blockIdx.z;
  const bf16_t* A = z ? alphaT : alpha;
  const bf16_t* B = z ? aaT : bvT;
  const float* res = z ? resV : resA;
  float* o = out + (size_t)z * NA_DIM * D_DIM;
  const int bm = blockIdx.x * 128, bn = blockIdx.y * 128;
  f32x4 acc[4][4] = {};
  gemm4w64(A, B, 4096, bm, bn, lds, acc);

  const int lane = threadIdx.x & 63;
  const int wid = threadIdx.x >> 6;
  const int wm = wid >> 1, wn = wid & 1;
  const int frow = lane & 15, hi = lane >> 4;
  const int row0 = bm + wm * 64 + hi * 4;
  const int col0 = bn + wn * 64 + frow;
#pragma unroll
  for (int rf = 0; rf < 4; ++rf)
#pragma unroll
    for (int fc = 0; fc < 4; ++fc)
#pragma unroll
      for (int r = 0; r < 4; ++r) {
        size_t idx = (size_t)(row0 + rf * 16 + r) * D_DIM + (col0 + fc * 16);
        o[idx] = acc[rf][fc][r] + res[idx];
      }
}

// ---------------- f32 -> bf16 convert, ONE launch (6 z-slices) ----------------
__global__ __launch_bounds__(256) void cvt_all(
    const float* __restrict__ i0, const float* __restrict__ i1,
    const float* __restrict__ i2, const float* __restrict__ i3,
    const float* __restrict__ i4, const float* __restrict__ i5,
    bf16_t* __restrict__ o0, bf16_t* __restrict__ o1,
    bf16_t* __restrict__ o2, bf16_t* __restrict__ o3,
    bf16_t* __restrict__ o4, bf16_t* __restrict__ o5) {
  const int z = blockIdx.y;
  // slices 0,1: 4M elems (2048 blocks); slices 2..5: 1M elems (512 blocks)
  if (z >= 2 && blockIdx.x >= 512) return;
  const float* in = (z == 0) ? i0 : (z == 1) ? i1 : (z == 2) ? i2
                  : (z == 3) ? i3 : (z == 4) ? i4 : i5;
  bf16_t* out = (z == 0) ? o0 : (z == 1) ? o1 : (z == 2) ? o2
              : (z == 3) ? o3 : (z == 4) ? o4 : o5;
  int i = (blockIdx.x * 256 + threadIdx.x) * 8;
  float4 v0 = *(const float4*)(in + i);
  float4 v1 = *(const float4*)(in + i + 4);
  bf16x8 o;
  o[0] = (bf16_t)v0.x; o[1] = (bf16_t)v0.y; o[2] = (bf16_t)v0.z; o[3] = (bf16_t)v0.w;
  o[4] = (bf16_t)v1.x; o[5] = (bf16_t)v1.y; o[6] = (bf16_t)v1.z; o[7] = (bf16_t)v1.w;
  *(bf16x8*)(out + i) = o;
}

// ---------------- row softmax: f32 [rows][4096] -> bf16 alpha ----------------
__global__ __launch_bounds__(256) void softmax_rows(const float* __restrict__ S,
                                                    bf16_t* __restrict__ P) {
  const int row = blockIdx.x;
  const int ncol = 4096;
  const float* s = S + (size_t)row * ncol;
  const int base = threadIdx.x * 16;
  float v[16];
  float4* vp = (float4*)v;
#pragma unroll
  for (int q = 0; q < 4; ++q) vp[q] = *(const float4*)(s + base + q * 4);
  float m = v[0];
#pragma unroll
  for (int q = 1; q < 16; ++q) m = fmaxf(m, v[q]);
  for (int off = 32; off; off >>= 1) m = fmaxf(m, __shfl_xor(m, off));
  __shared__ float sm[4], ss[4];
  const int wid = threadIdx.x >> 6, lane = threadIdx.x & 63;
  if (lane == 0) sm[wid] = m;
  __syncthreads();
  m = fmaxf(fmaxf(sm[0], sm[1]), fmaxf(sm[2], sm[3]));
  float sum = 0.f;
#pragma unroll
  for (int q = 0; q < 16; ++q) { v[q] = __expf(v[q] - m); sum += v[q]; }
  for (int off = 32; off; off >>= 1) sum += __shfl_xor(sum, off);
  if (lane == 0) ss[wid] = sum;
  __syncthreads();
  const float inv = 1.0f / (ss[0] + ss[1] + ss[2] + ss[3]);
  bf16x8 o0, o1;
#pragma unroll
  for (int q = 0; q < 8; ++q) { o0[q] = (bf16_t)(v[q] * inv); o1[q] = (bf16_t)(v[q + 8] * inv); }
  bf16_t* p = P + (size_t)row * ncol + base;
  *(bf16x8*)p = o0;
  *(bf16x8*)(p + 8) = o1;
}

// ---------------- bf16 transpose: in[R][C] -> out[C][R], 64x64 LDS tiles ----------------
__global__ __launch_bounds__(256) void transpose_bf16(const bf16_t* __restrict__ in,
                                                      bf16_t* __restrict__ out, int R, int C) {
  __shared__ bf16_t t[64][72];
  const int bx = blockIdx.x * 64;
  const int by = blockIdx.y * 64;
  const int tid = threadIdx.x;
  const int c8 = (tid & 7) * 8;
  const int r = tid >> 3;
#pragma unroll
  for (int rr = 0; rr < 64; rr += 32) {
    bf16x8 v = *(const bf16x8*)(in + (size_t)(by + r + rr) * C + bx + c8);
    *(bf16x8*)&t[r + rr][c8] = v;
  }
  __syncthreads();
#pragma unroll
  for (int rr = 0; rr < 64; rr += 32) {
    bf16x8 v;
#pragma unroll
    for (int q = 0; q < 8; ++q) v[q] = t[c8 + q][r + rr];
    *(bf16x8*)(out + (size_t)(bx + r + rr) * R + by + c8) = v;
  }
}

extern "C" void kernel_launch(void* const* d_in, const int* in_sizes, int n_in,
                              void* d_out, int out_size, void* d_ws, size_t ws_size,
                              hipStream_t stream) {
  (void)in_sizes; (void)n_in; (void)out_size; (void)ws_size;
  const float* inA = (const float*)d_in[0];
  const float* inV = (const float*)d_in[1];
  const float* wBa = (const float*)d_in[2];
  const float* wAa = (const float*)d_in[3];
  const float* wBv = (const float*)d_in[4];
  const float* wAv = (const float*)d_in[5];
  float* out = (float*)d_out;

  // workspace layout (~170 MB)
  char* w = (char*)d_ws;
  auto take = [&](size_t bytes) { void* p = (void*)w; w += bytes; return p; };
  const size_t XB = (size_t)NA_DIM * D_DIM * 2;   // 8 MB
  const size_t WB = (size_t)D_DIM * D_DIM * 2;    // 2 MB
  bf16_t* XaB = (bf16_t*)take(XB);
  bf16_t* XvB = (bf16_t*)take(XB);
  bf16_t* WBaB = (bf16_t*)take(WB);
  bf16_t* WAaB = (bf16_t*)take(WB);
  bf16_t* WBvB = (bf16_t*)take(WB);
  bf16_t* WAvB = (bf16_t*)take(WB);
  bf16_t* b_a = (bf16_t*)take(XB);
  bf16_t* a_v = (bf16_t*)take(XB);
  bf16_t* a_aT = (bf16_t*)take(XB);   // [1024][4096], written directly by proj4 z=1
  bf16_t* b_vT = (bf16_t*)take(XB);   // [1024][4096], written directly by proj4 z=3
  float* scores = (float*)take((size_t)NA_DIM * NV_DIM * 4);   // 64 MB
  bf16_t* alpha = (bf16_t*)take((size_t)NA_DIM * NV_DIM * 2);  // 32 MB
  bf16_t* alphaT = (bf16_t*)take((size_t)NA_DIM * NV_DIM * 2); // 32 MB

  // converts: one launch, 6 slices (inputs 2048 blocks, weights 512 + early-exit)
  cvt_all<<<dim3(NA_DIM * D_DIM / 2048, 6), 256, 0, stream>>>(
      inA, inV, wBa, wAa, wAv, wBv, XaB, XvB, WBaB, WAaB, WAvB, WBvB);

  // stage 1: 4 projections (8-wave 256^2 core); z=1 -> a_aT, z=3 -> b_vT transposed
  gemm_proj4<<<dim3(NA_DIM / 256, D_DIM / 256, 4), 512, 0, stream>>>(
      XaB, XvB, WBaB, WAaB, WAvB, WBvB, b_a, a_aT, a_v, b_vT);

  // stage 2: scores (8-wave 256^2 core)
  gemm_scores<<<dim3(NA_DIM / 256, NV_DIM / 256), 512, 0, stream>>>(b_a, a_v, scores);

  // stage 3: row softmax -> bf16 alpha
  softmax_rows<<<NA_DIM, 256, 0, stream>>>(scores, alpha);

  // alpha transpose (only remaining transpose)
  transpose_bf16<<<dim3(NV_DIM / 64, NA_DIM / 64), 256, 0, stream>>>(alpha, alphaT, NA_DIM, NV_DIM);

  // stages 4+5: 4-wave 128^2 core, 2 blocks/CU, full K, fused residual
  gemm_att<<<dim3(NA_DIM / 128, D_DIM / 128, 2), 256, 0, stream>>>(
      alpha, b_vT, alphaT, a_aT, inA, inV, out);
}

// Round 21
// 189.586 us; speedup vs baseline: 1.0166x; 1.0166x over previous
//
#include <hip/hip_runtime.h>
#include <stdint.h>

#define D_DIM 1024
#define NA_DIM 4096
#define NV_DIM 4096

typedef __bf16 bf16_t;
typedef __bf16 bf16x4 __attribute__((ext_vector_type(4)));
typedef __bf16 bf16x8 __attribute__((ext_vector_type(8)));
typedef float f32x4 __attribute__((ext_vector_type(4)));

// async global->LDS, 16B per lane; LDS base must be wave-uniform (HW adds lane*16)
__device__ __forceinline__ void gload_lds16(const void* g, void* lds) {
  __builtin_amdgcn_global_load_lds(
      (const __attribute__((address_space(1))) unsigned int*)g,
      (__attribute__((address_space(3))) unsigned int*)lds, 16, 0, 0);
}

// FINAL HYBRID (r20 consolidation): each stage uses its measured-best core.
//  - proj4/scores: 8-wave 256x256 "loose" core (r13/r15/r19: ~33us each at K=1024).
//  - att: 4-wave 128x128 BK=64 core, 64KB LDS -> 2 blocks/CU (r18-r20: ~73.5us;
//    co-resident blocks overlap LDS/MFMA phases across independent barrier domains).
//    NEW r21: s_setprio(1) around att's MFMA cluster - T5 applies ONLY here because
//    the two co-resident blocks are measurably de-phased (m191 regime: independent
//    blocks at different phases; m190 showed null/negative for lockstep 1-block/CU,
//    which is why the 256^2 cores do NOT get setprio).
//  - cvt merged to one launch; transposed projection stores; fused residual epilogue.
// r12 lesson stands: no device-fence cross-block fusion on non-coherent-L2 XCDs.
#define VMW(N) asm volatile("s_waitcnt vmcnt(" #N ")" ::: "memory")
#define LKW(N) asm volatile("s_waitcnt lgkmcnt(" #N ")" ::: "memory")
#define BAR() asm volatile("s_barrier" ::: "memory")
#define MFMA(a, b, c) __builtin_amdgcn_mfma_f32_16x16x32_bf16((a), (b), (c), 0, 0, 0)

// ====== 8-wave 256x256 GEMM core, BK=64, 128KB LDS (1 block/CU) ======
// T2 swizzle: 16B chunk pc holds logical chunk pc ^ (row&7), both sides (conflicts=0).
__device__ __forceinline__ void gemm256_loose(const bf16_t* __restrict__ A,
                                              const bf16_t* __restrict__ B,
                                              int K, int bm, int bn,
                                              bf16_t* lds, f32x4 acc[8][4]) {
  const int tid = threadIdx.x;
  const int lane = tid & 63;
  const int wid = tid >> 6;
  const int wm = wid >> 2;   // 0..1 : wave row-half (128 rows)
  const int wn = wid & 3;    // 0..3 : wave col-quarter (64 cols)
  const int frow = lane & 15;
  const int hi = lane >> 4;
  const int fko = ((hi ^ (frow & 7)) << 3);

  const int sr = (wid << 4) + (lane >> 3);              // 0..127 within half-tile
  const int sc = (((lane & 7) ^ (lane >> 3)) << 3);
  const bf16_t* pAs = A + (size_t)(bm + sr) * K + sc;
  const bf16_t* pBs = B + (size_t)(bn + sr) * K + sc;
  const int dstW = wid << 10;

  const int aBase = (wm << 13) + frow * 64 + fko;
  const int bBase = 16384 + ((wn >> 1) << 13) + ((wn & 1) << 12) + frow * 64 + fko;

#define STG_A(kt, h, bufb) do { \
    const bf16_t* s_ = pAs + (size_t)((h) * 128) * K + (size_t)(kt) * 64; \
    bf16_t* d_ = lds + (bufb) * 32768 + (h) * 8192 + dstW; \
    gload_lds16(s_, d_); gload_lds16(s_ + (size_t)8 * K, d_ + 512); } while (0)
#define STG_B(kt, h, bufb) do { \
    const bf16_t* s_ = pBs + (size_t)((h) * 128) * K + (size_t)(kt) * 64; \
    bf16_t* d_ = lds + (bufb) * 32768 + 16384 + (h) * 8192 + dstW; \
    gload_lds16(s_, d_); gload_lds16(s_ + (size_t)8 * K, d_ + 512); } while (0)

#define TILE(P, T) do { \
    if ((T) + 1 < NT) { \
      STG_A((T) + 1, 0, (P) ^ 1); STG_A((T) + 1, 1, (P) ^ 1); \
      STG_B((T) + 1, 0, (P) ^ 1); STG_B((T) + 1, 1, (P) ^ 1); \
    } \
    { \
      const bf16_t* Lb_ = lds + (P) * 32768; \
      bf16x8 bf0[4], bf1[4]; \
      _Pragma("unroll") for (int fc = 0; fc < 4; ++fc) { \
        bf0[fc] = *(const bf16x8*)&Lb_[bBase + fc * 1024]; \
        bf1[fc] = *(const bf16x8*)&Lb_[(bBase ^ 32) + fc * 1024]; \
      } \
      _Pragma("unroll") for (int q = 0; q < 4; ++q) { \
        bf16x8 a0 = *(const bf16x8*)&Lb_[aBase + q * 2048]; \
        bf16x8 a1 = *(const bf16x8*)&Lb_[(aBase ^ 32) + q * 2048]; \
        bf16x8 a2 = *(const bf16x8*)&Lb_[aBase + q * 2048 + 1024]; \
        bf16x8 a3 = *(const bf16x8*)&Lb_[(aBase ^ 32) + q * 2048 + 1024]; \
        _Pragma("unroll") for (int fc = 0; fc < 4; ++fc) { \
          acc[q * 2][fc]     = MFMA(a0, bf0[fc], acc[q * 2][fc]); \
          acc[q * 2][fc]     = MFMA(a1, bf1[fc], acc[q * 2][fc]); \
          acc[q * 2 + 1][fc] = MFMA(a2, bf0[fc], acc[q * 2 + 1][fc]); \
          acc[q * 2 + 1][fc] = MFMA(a3, bf1[fc], acc[q * 2 + 1][fc]); \
        } \
      } \
    } \
    LKW(0); VMW(0); BAR(); \
  } while (0)

  const int NT = K >> 6;

  STG_A(0, 0, 0); STG_A(0, 1, 0); STG_B(0, 0, 0); STG_B(0, 1, 0);
  VMW(0);
  BAR();

  for (int it = 0; it < (NT >> 1); ++it) {
    TILE(0, 2 * it);
    TILE(1, 2 * it + 1);
  }
#undef TILE
#undef STG_A
#undef STG_B
}

// ====== 4-wave 128x128 GEMM core, BK=64, 64KB LDS -> 2 blocks/CU (att) ======
// setprio around the MFMA cluster (T5): pays ONLY with de-phased co-resident blocks.
__device__ __forceinline__ void gemm4w64(const bf16_t* __restrict__ A,
                                         const bf16_t* __restrict__ B,
                                         int K, int bm, int bn,
                                         bf16_t* lds, f32x4 acc[4][4]) {
  const int tid = threadIdx.x;           // 0..255
  const int lane = tid & 63;
  const int wid = tid >> 6;              // 0..3
  const int wm = wid >> 1, wn = wid & 1;
  const int frow = lane & 15;
  const int hi = lane >> 4;
  const int fko = ((hi ^ (frow & 7)) << 3);

  const int r0 = tid >> 3;
  const int c0 = (((tid & 7) ^ (r0 & 7)) << 3);
  const bf16_t* pAs = A + (size_t)(bm + r0) * K + c0;
  const bf16_t* pBs = B + (size_t)(bn + r0) * K + c0;
  const int dstW = wid << 9;

  const int aBase = (wm << 12) + frow * 64 + fko;
  const int bBase = 8192 + (wn << 12) + frow * 64 + fko;

#define STG_A6(kt, bufb) do { \
    const bf16_t* s_ = pAs + (size_t)(kt) * 64; \
    bf16_t* d_ = lds + (bufb) * 16384 + dstW; \
    gload_lds16(s_, d_);                      gload_lds16(s_ + (size_t)32 * K, d_ + 2048); \
    gload_lds16(s_ + (size_t)64 * K, d_ + 4096); gload_lds16(s_ + (size_t)96 * K, d_ + 6144); } while (0)
#define STG_B6(kt, bufb) do { \
    const bf16_t* s_ = pBs + (size_t)(kt) * 64; \
    bf16_t* d_ = lds + (bufb) * 16384 + 8192 + dstW; \
    gload_lds16(s_, d_);                      gload_lds16(s_ + (size_t)32 * K, d_ + 2048); \
    gload_lds16(s_ + (size_t)64 * K, d_ + 4096); gload_lds16(s_ + (size_t)96 * K, d_ + 6144); } while (0)

#define TILE6(P, T) do { \
    if ((T) + 1 < NT) { STG_A6((T) + 1, (P) ^ 1); STG_B6((T) + 1, (P) ^ 1); } \
    { \
      const bf16_t* Lb_ = lds + (P) * 16384; \
      bf16x8 bf0[4], bf1[4]; \
      _Pragma("unroll") for (int fc = 0; fc < 4; ++fc) { \
        bf0[fc] = *(const bf16x8*)&Lb_[bBase + fc * 1024]; \
        bf1[fc] = *(const bf16x8*)&Lb_[(bBase ^ 32) + fc * 1024]; \
      } \
      __builtin_amdgcn_s_setprio(1); \
      _Pragma("unroll") for (int q = 0; q < 4; ++q) { \
        bf16x8 a0 = *(const bf16x8*)&Lb_[aBase + q * 1024]; \
        bf16x8 a1 = *(const bf16x8*)&Lb_[(aBase ^ 32) + q * 1024]; \
        _Pragma("unroll") for (int fc = 0; fc < 4; ++fc) { \
          acc[q][fc] = MFMA(a0, bf0[fc], acc[q][fc]); \
          acc[q][fc] = MFMA(a1, bf1[fc], acc[q][fc]); \
        } \
      } \
      __builtin_amdgcn_s_setprio(0); \
    } \
    LKW(0); VMW(0); BAR(); \
  } while (0)

  const int NT = K >> 6;

  STG_A6(0, 0); STG_B6(0, 0);
  VMW(0);
  BAR();

  for (int it = 0; it < (NT >> 1); ++it) {
    TILE6(0, 2 * it);
    TILE6(1, 2 * it + 1);
  }
#undef TILE6
#undef STG_A6
#undef STG_B6
}

// epilogues: verified C/D map: col = lane&15, row = (lane>>4)*4 + reg
template <int BF16OUT>
__device__ __forceinline__ void store256(void* Cv, int ldc, int bm, int bn, f32x4 acc[8][4]) {
  const int lane = threadIdx.x & 63;
  const int wid = threadIdx.x >> 6;
  const int wm = wid >> 2, wn = wid & 3;
  const int frow = lane & 15, hi = lane >> 4;
  const int row0 = bm + wm * 128 + hi * 4;
  const int col0 = bn + wn * 64 + frow;
#pragma unroll
  for (int rf = 0; rf < 8; ++rf)
#pragma unroll
    for (int fc = 0; fc < 4; ++fc)
#pragma unroll
      for (int r = 0; r < 4; ++r) {
        size_t idx = (size_t)(row0 + rf * 16 + r) * ldc + (col0 + fc * 16);
        if constexpr (BF16OUT) ((bf16_t*)Cv)[idx] = (bf16_t)acc[rf][fc][r];
        else ((float*)Cv)[idx] = acc[rf][fc][r];
      }
}

__device__ __forceinline__ void store256T(bf16_t* CT, int ldcT, int bm, int bn, f32x4 acc[8][4]) {
  const int lane = threadIdx.x & 63;
  const int wid = threadIdx.x >> 6;
  const int wm = wid >> 2, wn = wid & 3;
  const int frow = lane & 15, hi = lane >> 4;
  const int row0 = bm + wm * 128 + hi * 4;
  const int col0 = bn + wn * 64 + frow;
#pragma unroll
  for (int rf = 0; rf < 8; ++rf)
#pragma unroll
    for (int fc = 0; fc < 4; ++fc) {
      bf16x4 v;
#pragma unroll
      for (int r = 0; r < 4; ++r) v[r] = (bf16_t)acc[rf][fc][r];
      *(bf16x4*)(&CT[(size_t)(col0 + fc * 16) * ldcT + row0 + rf * 16]) = v;
    }
}

// ---------------- batched projections (8-wave 256^2 core); z=1,3 TRANSPOSED ----------
__global__ __launch_bounds__(512, 1) void gemm_proj4(
    const bf16_t* __restrict__ Xa, const bf16_t* __restrict__ Xv,
    const bf16_t* __restrict__ W0, const bf16_t* __restrict__ W1,
    const bf16_t* __restrict__ W2, const bf16_t* __restrict__ W3,
    bf16_t* __restrict__ C0, bf16_t* __restrict__ C1T,
    bf16_t* __restrict__ C2, bf16_t* __restrict__ C3T) {
  __shared__ bf16_t lds[65536];
  const int z = blockIdx.z;
  const bf16_t* A = (z < 2) ? Xa : Xv;
  const bf16_t* B = (z == 0) ? W0 : (z == 1) ? W1 : (z == 2) ? W2 : W3;
  f32x4 acc[8][4] = {};
  const int bm = blockIdx.x * 256, bn = blockIdx.y * 256;
  gemm256_loose(A, B, D_DIM, bm, bn, lds, acc);
  if (z == 0) store256<1>(C0, D_DIM, bm, bn, acc);
  else if (z == 1) store256T(C1T, NA_DIM, bm, bn, acc);
  else if (z == 2) store256<1>(C2, D_DIM, bm, bn, acc);
  else store256T(C3T, NV_DIM, bm, bn, acc);
}

// ---------------- scores GEMM (8-wave 256^2 core) ----------------
__global__ __launch_bounds__(512, 1) void gemm_scores(const bf16_t* __restrict__ A,
                                                      const bf16_t* __restrict__ B,
                                                      float* __restrict__ C) {
  __shared__ bf16_t lds[65536];
  f32x4 acc[8][4] = {};
  gemm256_loose(A, B, D_DIM, blockIdx.x * 256, blockIdx.y * 256, lds, acc);
  store256<0>(C, NV_DIM, blockIdx.x * 256, blockIdx.y * 256, acc);
}

// ------- stages 4/5 (4-wave 128^2 core, 2 blocks/CU), full K, fused residual -------
__global__ __launch_bounds__(256, 2) void gemm_att(
    const bf16_t* __restrict__ alpha, const bf16_t* __restrict__ bvT,
    const bf16_t* __restrict__ alphaT, const bf16_t* __restrict__ aaT,
    const float* __restrict__ resA, const float* __restrict__ resV,
    float* __restrict__ out) {
  __shared__ bf16_t lds[32768];
  const int z = blockIdx.z;
  const bf16_t* A = z ? alphaT : alpha;
  const bf16_t* B = z ? aaT : bvT;
  const float* res = z ? resV : resA;
  float* o = out + (size_t)z * NA_DIM * D_DIM;
  const int bm = blockIdx.x * 128, bn = blockIdx.y * 128;
  f32x4 acc[4][4] = {};
  gemm4w64(A, B, 4096, bm, bn, lds, acc);

  const int lane = threadIdx.x & 63;
  const int wid = threadIdx.x >> 6;
  const int wm = wid >> 1, wn = wid & 1;
  const int frow = lane & 15, hi = lane >> 4;
  const int row0 = bm + wm * 64 + hi * 4;
  const int col0 = bn + wn * 64 + frow;
#pragma unroll
  for (int rf = 0; rf < 4; ++rf)
#pragma unroll
    for (int fc = 0; fc < 4; ++fc)
#pragma unroll
      for (int r = 0; r < 4; ++r) {
        size_t idx = (size_t)(row0 + rf * 16 + r) * D_DIM + (col0 + fc * 16);
        o[idx] = acc[rf][fc][r] + res[idx];
      }
}

// ---------------- f32 -> bf16 convert, ONE launch (6 z-slices) ----------------
__global__ __launch_bounds__(256) void cvt_all(
    const float* __restrict__ i0, const float* __restrict__ i1,
    const float* __restrict__ i2, const float* __restrict__ i3,
    const float* __restrict__ i4, const float* __restrict__ i5,
    bf16_t* __restrict__ o0, bf16_t* __restrict__ o1,
    bf16_t* __restrict__ o2, bf16_t* __restrict__ o3,
    bf16_t* __restrict__ o4, bf16_t* __restrict__ o5) {
  const int z = blockIdx.y;
  // slices 0,1: 4M elems (2048 blocks); slices 2..5: 1M elems (512 blocks)
  if (z >= 2 && blockIdx.x >= 512) return;
  const float* in = (z == 0) ? i0 : (z == 1) ? i1 : (z == 2) ? i2
                  : (z == 3) ? i3 : (z == 4) ? i4 : i5;
  bf16_t* out = (z == 0) ? o0 : (z == 1) ? o1 : (z == 2) ? o2
              : (z == 3) ? o3 : (z == 4) ? o4 : o5;
  int i = (blockIdx.x * 256 + threadIdx.x) * 8;
  float4 v0 = *(const float4*)(in + i);
  float4 v1 = *(const float4*)(in + i + 4);
  bf16x8 o;
  o[0] = (bf16_t)v0.x; o[1] = (bf16_t)v0.y; o[2] = (bf16_t)v0.z; o[3] = (bf16_t)v0.w;
  o[4] = (bf16_t)v1.x; o[5] = (bf16_t)v1.y; o[6] = (bf16_t)v1.z; o[7] = (bf16_t)v1.w;
  *(bf16x8*)(out + i) = o;
}

// ---------------- row softmax: f32 [rows][4096] -> bf16 alpha ----------------
__global__ __launch_bounds__(256) void softmax_rows(const float* __restrict__ S,
                                                    bf16_t* __restrict__ P) {
  const int row = blockIdx.x;
  const int ncol = 4096;
  const float* s = S + (size_t)row * ncol;
  const int base = threadIdx.x * 16;
  float v[16];
  float4* vp = (float4*)v;
#pragma unroll
  for (int q = 0; q < 4; ++q) vp[q] = *(const float4*)(s + base + q * 4);
  float m = v[0];
#pragma unroll
  for (int q = 1; q < 16; ++q) m = fmaxf(m, v[q]);
  for (int off = 32; off; off >>= 1) m = fmaxf(m, __shfl_xor(m, off));
  __shared__ float sm[4], ss[4];
  const int wid = threadIdx.x >> 6, lane = threadIdx.x & 63;
  if (lane == 0) sm[wid] = m;
  __syncthreads();
  m = fmaxf(fmaxf(sm[0], sm[1]), fmaxf(sm[2], sm[3]));
  float sum = 0.f;
#pragma unroll
  for (int q = 0; q < 16; ++q) { v[q] = __expf(v[q] - m); sum += v[q]; }
  for (int off = 32; off; off >>= 1) sum += __shfl_xor(sum, off);
  if (lane == 0) ss[wid] = sum;
  __syncthreads();
  const float inv = 1.0f / (ss[0] + ss[1] + ss[2] + ss[3]);
  bf16x8 o0, o1;
#pragma unroll
  for (int q = 0; q < 8; ++q) { o0[q] = (bf16_t)(v[q] * inv); o1[q] = (bf16_t)(v[q + 8] * inv); }
  bf16_t* p = P + (size_t)row * ncol + base;
  *(bf16x8*)p = o0;
  *(bf16x8*)(p + 8) = o1;
}

// ---------------- bf16 transpose: in[R][C] -> out[C][R], 64x64 LDS tiles ----------------
__global__ __launch_bounds__(256) void transpose_bf16(const bf16_t* __restrict__ in,
                                                      bf16_t* __restrict__ out, int R, int C) {
  __shared__ bf16_t t[64][72];
  const int bx = blockIdx.x * 64;
  const int by = blockIdx.y * 64;
  const int tid = threadIdx.x;
  const int c8 = (tid & 7) * 8;
  const int r = tid >> 3;
#pragma unroll
  for (int rr = 0; rr < 64; rr += 32) {
    bf16x8 v = *(const bf16x8*)(in + (size_t)(by + r + rr) * C + bx + c8);
    *(bf16x8*)&t[r + rr][c8] = v;
  }
  __syncthreads();
#pragma unroll
  for (int rr = 0; rr < 64; rr += 32) {
    bf16x8 v;
#pragma unroll
    for (int q = 0; q < 8; ++q) v[q] = t[c8 + q][r + rr];
    *(bf16x8*)(out + (size_t)(bx + r + rr) * R + by + c8) = v;
  }
}

extern "C" void kernel_launch(void* const* d_in, const int* in_sizes, int n_in,
                              void* d_out, int out_size, void* d_ws, size_t ws_size,
                              hipStream_t stream) {
  (void)in_sizes; (void)n_in; (void)out_size; (void)ws_size;
  const float* inA = (const float*)d_in[0];
  const float* inV = (const float*)d_in[1];
  const float* wBa = (const float*)d_in[2];
  const float* wAa = (const float*)d_in[3];
  const float* wBv = (const float*)d_in[4];
  const float* wAv = (const float*)d_in[5];
  float* out = (float*)d_out;

  // workspace layout (~170 MB)
  char* w = (char*)d_ws;
  auto take = [&](size_t bytes) { void* p = (void*)w; w += bytes; return p; };
  const size_t XB = (size_t)NA_DIM * D_DIM * 2;   // 8 MB
  const size_t WB = (size_t)D_DIM * D_DIM * 2;    // 2 MB
  bf16_t* XaB = (bf16_t*)take(XB);
  bf16_t* XvB = (bf16_t*)take(XB);
  bf16_t* WBaB = (bf16_t*)take(WB);
  bf16_t* WAaB = (bf16_t*)take(WB);
  bf16_t* WBvB = (bf16_t*)take(WB);
  bf16_t* WAvB = (bf16_t*)take(WB);
  bf16_t* b_a = (bf16_t*)take(XB);
  bf16_t* a_v = (bf16_t*)take(XB);
  bf16_t* a_aT = (bf16_t*)take(XB);   // [1024][4096], written directly by proj4 z=1
  bf16_t* b_vT = (bf16_t*)take(XB);   // [1024][4096], written directly by proj4 z=3
  float* scores = (float*)take((size_t)NA_DIM * NV_DIM * 4);   // 64 MB
  bf16_t* alpha = (bf16_t*)take((size_t)NA_DIM * NV_DIM * 2);  // 32 MB
  bf16_t* alphaT = (bf16_t*)take((size_t)NA_DIM * NV_DIM * 2); // 32 MB

  // converts: one launch, 6 slices (inputs 2048 blocks, weights 512 + early-exit)
  cvt_all<<<dim3(NA_DIM * D_DIM / 2048, 6), 256, 0, stream>>>(
      inA, inV, wBa, wAa, wAv, wBv, XaB, XvB, WBaB, WAaB, WAvB, WBvB);

  // stage 1: 4 projections (8-wave 256^2 core); z=1 -> a_aT, z=3 -> b_vT transposed
  gemm_proj4<<<dim3(NA_DIM / 256, D_DIM / 256, 4), 512, 0, stream>>>(
      XaB, XvB, WBaB, WAaB, WAvB, WBvB, b_a, a_aT, a_v, b_vT);

  // stage 2: scores (8-wave 256^2 core)
  gemm_scores<<<dim3(NA_DIM / 256, NV_DIM / 256), 512, 0, stream>>>(b_a, a_v, scores);

  // stage 3: row softmax -> bf16 alpha
  softmax_rows<<<NA_DIM, 256, 0, stream>>>(scores, alpha);

  // alpha transpose (only remaining transpose)
  transpose_bf16<<<dim3(NV_DIM / 64, NA_DIM / 64), 256, 0, stream>>>(alpha, alphaT, NA_DIM, NV_DIM);

  // stages 4+5: 4-wave 128^2 core (setprio'd), 2 blocks/CU, full K, fused residual
  gemm_att<<<dim3(NA_DIM / 128, D_DIM / 128, 2), 256, 0, stream>>>(
      alpha, b_vT, alphaT, a_aT, inA, inV, out);
}